// Round 2
// baseline (757.013 us; speedup 1.0000x reference)
//
#include <hip/hip_runtime.h>
#include <math.h>

// 31x31 depthwise Gaussian (sigma=3) == separable 25-tap Gaussian applied
// twice (outer 3 taps of the 31 are exactly zero). Reflection effectively at
// radius 12 (reference pads 15 but the extra taps are zero).
//
// R2 structure: stage raw tile -> LDS (coalesced burst loads, reflect handled
// here), horizontal pass from LDS (ds_read_b128), results held in regs,
// scatter to mid[] overlaid on the dead raw buffer, vertical sliding-window
// pass from LDS, coalesced stores. Symmetric kernel -> 13 weight VGPRs.

#define IW 512
#define IH 512
#define RAD 12
#define TW 64                 // output tile width
#define TH 32                 // output tile height
#define RROWS (TH + 2*RAD)    // 56 staged rows
#define RSTRIDE 100           // floats; 96 staged cols + 4 pad; 100%32==4 -> uniform banks
#define MSTRIDE 65            // mid stride; 65%32==1 -> conflict-free column reads
#define NQ 24                 // float4 quads staged per row (96 cols, from c0g-16)

__global__ __launch_bounds__(256, 6)
void gauss_blur_sep2_kernel(const float* __restrict__ x,
                            const float* __restrict__ wgt,
                            float* __restrict__ out)
{
    __shared__ float lds[RROWS * RSTRIDE];   // 5600 floats = 22400 B (raw, later mid)
    __shared__ float k1s[13];

    const int tid = threadIdx.x;
    const int z   = blockIdx.z;
    const int ch  = z % 3;

    // 1D kernel from 2D weight: w2d = outer(f,f); k1[t] = w2d[15][3+t]/sqrt(w2d[15][15]).
    // Symmetric: k1[t] == k1[24-t]; store t=0..12.
    if (tid < 13) {
        const float* wp = wgt + ch * 961;
        k1s[tid] = wp[15 * 31 + 3 + tid] / sqrtf(wp[15 * 31 + 15]);
    }

    const int r0g = blockIdx.y * TH;
    const int c0g = blockIdx.x * TW;
    const float* __restrict__ src = x + (size_t)z * (IW * IH);

    // ---------- phase A: stage raw tile into LDS (reflect at edges) ----------
    // rows r0g-12 .. r0g+43 (56), cols c0g-16 .. c0g+79 (96, float4-aligned)
    for (int u = tid; u < RROWS * NQ; u += 256) {
        const int r = u / NQ;
        const int q = u - r * NQ;
        int gr = r0g + r - RAD;
        gr = gr < 0 ? -gr : (gr >= IH ? 2 * IH - 2 - gr : gr);
        const int gc = c0g - 16 + 4 * q;
        float4 f;
        if (gc >= 0 && gc <= IW - 4) {
            f = *(const float4*)(src + (size_t)gr * IW + gc);
        } else {
            float tv[4];
#pragma unroll
            for (int j = 0; j < 4; ++j) {
                int g2 = gc + j;
                g2 = g2 < 0 ? -g2 : (g2 >= IW ? 2 * IW - 2 - g2 : g2);
                tv[j] = src[(size_t)gr * IW + g2];
            }
            f = make_float4(tv[0], tv[1], tv[2], tv[3]);
        }
        *(float4*)(&lds[r * RSTRIDE + 4 * q]) = f;
    }
    __syncthreads();

    float kk[13];
#pragma unroll
    for (int t = 0; t < 13; ++t) kk[t] = k1s[t];   // broadcast reads, free

    // ---------- phase B: horizontal pass from LDS, results in regs ----------
    // 448 tasks = 56 rows x 8 col-groups of 8 outputs. task0 = tid (all),
    // task1 = tid+256 (waves 0-2 only -> wave-uniform branch).
    float res0[8], res1[8];

    {
        const int g = tid & 7, m = tid >> 3;
        const float* __restrict__ base = &lds[m * RSTRIDE + 8 * g + 4];
        float v[32];
#pragma unroll
        for (int q = 0; q < 8; ++q) {
            float4 f = *(const float4*)(base + 4 * q);
            v[4*q+0] = f.x; v[4*q+1] = f.y; v[4*q+2] = f.z; v[4*q+3] = f.w;
        }
#pragma unroll
        for (int o = 0; o < 8; ++o) {
            float acc = v[o + 12] * kk[12];
#pragma unroll
            for (int t = 0; t < 12; ++t)
                acc = fmaf(v[o + t] + v[o + 24 - t], kk[t], acc);
            res0[o] = acc;
        }
    }
    const int task1 = tid + 256;
    if (task1 < RROWS * 8) {          // tid < 192: waves 0..2, uniform
        const int g = task1 & 7, m = task1 >> 3;
        const float* __restrict__ base = &lds[m * RSTRIDE + 8 * g + 4];
        float v[32];
#pragma unroll
        for (int q = 0; q < 8; ++q) {
            float4 f = *(const float4*)(base + 4 * q);
            v[4*q+0] = f.x; v[4*q+1] = f.y; v[4*q+2] = f.z; v[4*q+3] = f.w;
        }
#pragma unroll
        for (int o = 0; o < 8; ++o) {
            float acc = v[o + 12] * kk[12];
#pragma unroll
            for (int t = 0; t < 12; ++t)
                acc = fmaf(v[o + t] + v[o + 24 - t], kk[t], acc);
            res1[o] = acc;
        }
    }
    __syncthreads();

    // ---------- phase C: scatter horizontal results to mid (overlays raw) ----------
    {
        const int g = tid & 7, m = tid >> 3;
#pragma unroll
        for (int o = 0; o < 8; ++o) lds[m * MSTRIDE + 8 * g + o] = res0[o];
    }
    if (task1 < RROWS * 8) {
        const int g = task1 & 7, m = task1 >> 3;
#pragma unroll
        for (int o = 0; o < 8; ++o) lds[m * MSTRIDE + 8 * g + o] = res1[o];
    }
    __syncthreads();

    // ---------- phase D: vertical sliding-window pass, coalesced stores ----------
    // lanes span 64 contiguous cols (conflict-free, coalesced); each thread
    // 1 col x 8 rows: 32 LDS reads feed 200 FMAs.
    const int c  = tid & 63;
    const int rb = (tid >> 6) * 8;

    float acc[8];
#pragma unroll
    for (int o = 0; o < 8; ++o) acc[o] = 0.f;

#pragma unroll
    for (int m2 = 0; m2 < 32; ++m2) {
        const float vv = lds[(rb + m2) * MSTRIDE + c];
#pragma unroll
        for (int o = 0; o < 8; ++o) {
            const int t = m2 - o;
            if (t >= 0 && t < 25) {
                const float w = (t <= 12) ? kk[t] : kk[24 - t];
                acc[o] = fmaf(vv, w, acc[o]);
            }
        }
    }

    float* __restrict__ dst = out + (size_t)z * (IW * IH) + (size_t)(r0g + rb) * IW + c0g + c;
#pragma unroll
    for (int o = 0; o < 8; ++o) {
        dst[(size_t)o * IW] = acc[o];
    }
}

extern "C" void kernel_launch(void* const* d_in, const int* in_sizes, int n_in,
                              void* d_out, int out_size, void* d_ws, size_t ws_size,
                              hipStream_t stream)
{
    const float* x   = (const float*)d_in[0];
    const float* wgt = (const float*)d_in[1];
    float* out = (float*)d_out;

    dim3 grid(IW / TW, IH / TH, 96);   // 8 x 16 x 96 = 12288 blocks
    gauss_blur_sep2_kernel<<<grid, dim3(256), 0, stream>>>(x, wgt, out);
}

// Round 3
// 242.865 us; speedup vs baseline: 3.1170x; 3.1170x over previous
//
#include <hip/hip_runtime.h>
#include <math.h>

// 31x31 depthwise Gaussian (sigma=3) == separable 25-tap Gaussian applied
// twice (outer 3 taps of the 31 are exactly zero). Reflection effectively at
// radius 12 (reference pads 15 but the outer taps are zero).
//
// R3: R2 structure minus the spill bomb. No min-waves launch_bounds (R2's
// (256,6) forced VGPR=40 -> 2.6 GB scratch spill traffic -> 650 us).
// Separate raw/mid LDS buffers: phase B reads raw -> writes mid with no
// barrier in between and no result arrays held across a barrier.

#define IW 512
#define IH 512
#define RAD 12
#define TW 64                 // output tile width
#define TH 32                 // output tile height
#define RROWS (TH + 2*RAD)    // 56 staged rows
#define RSTRIDE 100           // floats: 96 staged cols + 4 pad (100%32==4)
#define MSTRIDE 65            // mid stride: 65%32==1 -> conflict-free columns
#define NQ 24                 // float4 quads per staged row (96 cols from c0g-16)
#define NTASKA (RROWS * NQ)   // 1344 staging quads per block

__global__ __launch_bounds__(256)
void gauss_blur_sep3_kernel(const float* __restrict__ x,
                            const float* __restrict__ wgt,
                            float* __restrict__ out)
{
    __shared__ float raw[RROWS * RSTRIDE];   // 5600 floats = 22400 B
    __shared__ float mid[RROWS * MSTRIDE];   // 3640 floats = 14560 B
    __shared__ float k1s[13];

    const int tid = threadIdx.x;
    const int z   = blockIdx.z;
    const int ch  = z % 3;

    // 1D kernel from 2D weight: w2d = outer(f,f); k1[t] = w2d[15][3+t]/sqrt(w2d[15][15]).
    // Symmetric: k1[t] == k1[24-t]; store t=0..12.
    if (tid < 13) {
        const float* wp = wgt + ch * 961;
        k1s[tid] = wp[15 * 31 + 3 + tid] / sqrtf(wp[15 * 31 + 15]);
    }

    const int r0g = blockIdx.y * TH;
    const int c0g = blockIdx.x * TW;
    const float* __restrict__ src = x + (size_t)z * (IW * IH);

    // ---------- phase A: stage raw 56x96 tile into LDS (reflect at edges) ----
    // rows r0g-12 .. r0g+43, cols c0g-16 .. c0g+79 (float4-aligned).
    // Unrolled 6 slots so all global loads can be in flight together.
#pragma unroll
    for (int i = 0; i < 6; ++i) {
        const int u = tid + i * 256;
        if (i < 5 || u < NTASKA) {
            const int r = u / NQ;
            const int q = u - r * NQ;
            int gr = r0g + r - RAD;
            gr = gr < 0 ? -gr : (gr >= IH ? 2 * IH - 2 - gr : gr);
            const int gc = c0g - 16 + 4 * q;
            float4 f;
            if (gc >= 0 && gc <= IW - 4) {
                f = *(const float4*)(src + (size_t)gr * IW + gc);
            } else {
                float tv[4];
#pragma unroll
                for (int j = 0; j < 4; ++j) {
                    int g2 = gc + j;
                    g2 = g2 < 0 ? -g2 : (g2 >= IW ? 2 * IW - 2 - g2 : g2);
                    tv[j] = src[(size_t)gr * IW + g2];
                }
                f = make_float4(tv[0], tv[1], tv[2], tv[3]);
            }
            *(float4*)(&raw[r * RSTRIDE + 4 * q]) = f;
        }
    }
    __syncthreads();

    float kk[13];
#pragma unroll
    for (int t = 0; t < 13; ++t) kk[t] = k1s[t];   // broadcast reads, free

    // ---------- phase B: horizontal pass, raw (LDS) -> mid (LDS) ------------
    // 448 tasks = 56 rows x 8 groups of 8 outputs; no barrier needed inside
    // (reads raw, writes mid). Second slot covers tid<192 -> wave-uniform.
#pragma unroll
    for (int i = 0; i < 2; ++i) {
        const int task = tid + i * 256;
        if (i == 0 || task < RROWS * 8) {
            const int g = task & 7, m = task >> 3;
            const float* __restrict__ base = &raw[m * RSTRIDE + 8 * g + 4];
            float v[32];
#pragma unroll
            for (int q = 0; q < 8; ++q) {
                float4 f = *(const float4*)(base + 4 * q);
                v[4*q+0] = f.x; v[4*q+1] = f.y; v[4*q+2] = f.z; v[4*q+3] = f.w;
            }
#pragma unroll
            for (int o = 0; o < 8; ++o) {
                float acc = v[o + 12] * kk[12];
#pragma unroll
                for (int t = 0; t < 12; ++t)
                    acc = fmaf(v[o + t] + v[o + 24 - t], kk[t], acc);
                mid[m * MSTRIDE + 8 * g + o] = acc;
            }
        }
    }
    __syncthreads();

    // ---------- phase D: vertical sliding-window pass, coalesced stores -----
    // lanes span 64 contiguous cols (conflict-free LDS, coalesced stores);
    // each thread: 1 col x 8 rows, 32 LDS reads feed 200 FMAs.
    const int c  = tid & 63;
    const int rb = (tid >> 6) * 8;

    float acc[8];
#pragma unroll
    for (int o = 0; o < 8; ++o) acc[o] = 0.f;

#pragma unroll
    for (int m2 = 0; m2 < 32; ++m2) {
        const float vv = mid[(rb + m2) * MSTRIDE + c];
#pragma unroll
        for (int o = 0; o < 8; ++o) {
            const int t = m2 - o;
            if (t >= 0 && t < 25) {
                const float w = (t <= 12) ? kk[t] : kk[24 - t];
                acc[o] = fmaf(vv, w, acc[o]);
            }
        }
    }

    float* __restrict__ dst = out + (size_t)z * (IW * IH) + (size_t)(r0g + rb) * IW + c0g + c;
#pragma unroll
    for (int o = 0; o < 8; ++o) {
        dst[(size_t)o * IW] = acc[o];
    }
}

extern "C" void kernel_launch(void* const* d_in, const int* in_sizes, int n_in,
                              void* d_out, int out_size, void* d_ws, size_t ws_size,
                              hipStream_t stream)
{
    const float* x   = (const float*)d_in[0];
    const float* wgt = (const float*)d_in[1];
    float* out = (float*)d_out;

    dim3 grid(IW / TW, IH / TH, 96);   // 8 x 16 x 96 = 12288 blocks
    gauss_blur_sep3_kernel<<<grid, dim3(256), 0, stream>>>(x, wgt, out);
}